// Round 9
// baseline (2769.303 us; speedup 1.0000x reference)
//
#include <hip/hip_runtime.h>
#include <math.h>

#define NVOX 60000

typedef __attribute__((ext_vector_type(8))) short short8v;            // 8 bf16 raw
typedef __attribute__((ext_vector_type(8))) unsigned short ushort8v;  // 8 bf16 raw
typedef __attribute__((ext_vector_type(4))) float f32x4;

static __device__ __forceinline__ unsigned short f2bf(float f) {
    unsigned u = __float_as_uint(f);
    unsigned r = (u + 0x7fffu + ((u >> 16) & 1u)) >> 16;
    return (unsigned short)r;
}
static __device__ __forceinline__ float bf2f(unsigned short h) {
    return __uint_as_float(((unsigned)h) << 16);
}
// async global->LDS 16B per lane: dest = lds_base + lane*16 (wave-uniform base)
static __device__ __forceinline__ void gll16(const unsigned short* g, unsigned short* l) {
    __builtin_amdgcn_global_load_lds(
        (const __attribute__((address_space(1))) unsigned*)g,
        (__attribute__((address_space(3))) unsigned*)l,
        16, 0, 0);
}

// ---------------------------------------------------------------- pos embed (bf16 out)
__global__ __launch_bounds__(256) void pos_kernel(const float* __restrict__ ciw,
                                                  unsigned short* __restrict__ pos) {
    int idx = blockIdx.x * 256 + threadIdx.x;
    if (idx >= NVOX * 128) return;
    int n = idx >> 7, d = idx & 127;
    int c = d >> 6, t = (d & 63) >> 1;
    float xy = ciw[n * 2 + c] - 6.0f;
    float inv = exp2f((float)t * (13.287712379549449f / 32.0f)); // 10000^(t/32)
    float e = xy / inv;
    pos[idx] = f2bf((d & 1) ? cosf(e) : sinf(e));
}

// ------------------------------------------------------- fp32 -> bf16 convert
__global__ __launch_bounds__(256) void cvt_bf16(const float* __restrict__ in,
                                                unsigned short* __restrict__ out, int n) {
    int idx = blockIdx.x * 256 + threadIdx.x;
    if (idx < n) out[idx] = f2bf(in[idx]);
}

// -------------------------------------------- feat init: f32 copy + bf16 shadow
__global__ __launch_bounds__(256) void feat_init(const float* __restrict__ vf,
                                                 float* __restrict__ feat,
                                                 unsigned short* __restrict__ featb) {
    int idx = blockIdx.x * 256 + threadIdx.x;
    if (idx >= NVOX * 128) return;
    float v = vf[idx];
    feat[idx] = v;
    featb[idx] = f2bf(v);
}

// ----------------------------------------- MFMA GEMM (QKV): C = (A(+pos))*W^T + b
template<int KTOT, bool ADD, bool GELU, bool CBF16, bool LNF>
__global__ __launch_bounds__(256) void gemm_mfma(
    const unsigned short* __restrict__ A, const unsigned short* __restrict__ Aadd, int add_nblk,
    const unsigned short* __restrict__ W, const float* __restrict__ bias,
    void* __restrict__ Cp, int M, int ldc)
{
    __shared__ unsigned short smem[128 * 128];   // As(16KB) + Ws(16KB), reused as Cs(32KB)
    unsigned short* As = smem;
    unsigned short* Ws = smem + 128 * 64;
    const int tid = threadIdx.x;
    const int lane = tid & 63, wave = tid >> 6;
    const int wr = wave >> 1, wc = wave & 1;
    const int llo = lane & 15, lhi = lane >> 4;
    const int m0 = blockIdx.x * 128;
    const int n0 = blockIdx.y * 128;
    const bool addp = ADD && ((int)blockIdx.y < add_nblk);
    const int gr = lane >> 3;           // row within 8-row group
    const int gc = (lane & 7) ^ gr;     // pre-swizzled source chunk
    f32x4 acc[4][4] = {};

    for (int k0 = 0; k0 < KTOT; k0 += 64) {
        #pragma unroll
        for (int p = 0; p < 4; ++p) {
            int r0 = wave * 32 + p * 8;
            gll16(W + (size_t)(n0 + r0 + gr) * KTOT + k0 + gc * 8, &Ws[r0 * 64]);
        }
        if (!addp) {
            #pragma unroll
            for (int p = 0; p < 4; ++p) {
                int r0 = wave * 32 + p * 8;
                gll16(A + (size_t)(m0 + r0 + gr) * KTOT + k0 + gc * 8, &As[r0 * 64]);
            }
        } else {
            #pragma unroll
            for (int p = 0; p < 4; ++p) {
                int c = tid + p * 256;
                int r = c >> 3, c16 = c & 7;
                int m = m0 + r;
                short8v av = {};
                if (m < M) {
                    ushort8v fa = *reinterpret_cast<const ushort8v*>(A + (size_t)m * KTOT + k0 + c16 * 8);
                    ushort8v pa = *reinterpret_cast<const ushort8v*>(Aadd + (size_t)m * 128 + k0 + c16 * 8);
                    #pragma unroll
                    for (int q = 0; q < 8; ++q) av[q] = (short)f2bf(bf2f(fa[q]) + bf2f(pa[q]));
                }
                *reinterpret_cast<short8v*>((char*)As + r * 128 + ((c16 * 16) ^ ((r & 7) << 4))) = av;
            }
        }
        __syncthreads();
        #pragma unroll
        for (int kk = 0; kk < 2; ++kk) {
            int kb = kk * 64 + lhi * 16;
            short8v af[4], bf[4];
            #pragma unroll
            for (int i = 0; i < 4; ++i) {
                int r = wr * 64 + i * 16 + llo;
                af[i] = *reinterpret_cast<const short8v*>((const char*)As + r * 128 + (kb ^ ((r & 7) << 4)));
                int cc = wc * 64 + i * 16 + llo;
                bf[i] = *reinterpret_cast<const short8v*>((const char*)Ws + cc * 128 + (kb ^ ((cc & 7) << 4)));
            }
            #pragma unroll
            for (int i = 0; i < 4; ++i)
                #pragma unroll
                for (int j = 0; j < 4; ++j)
                    acc[i][j] = __builtin_amdgcn_mfma_f32_16x16x32_bf16(af[i], bf[j], acc[i][j], 0, 0, 0);
        }
        __syncthreads();
    }

    #pragma unroll
    for (int j = 0; j < 4; ++j) {
        int nl = wc * 64 + j * 16 + llo;
        float bn = bias[n0 + nl];
        #pragma unroll
        for (int i = 0; i < 4; ++i)
            #pragma unroll
            for (int rg = 0; rg < 4; ++rg) {
                float v = acc[i][j][rg] + bn;
                if (GELU) v = 0.5f * v * (1.0f + erff(v * 0.7071067811865475f));
                smem[(wr * 64 + i * 16 + lhi * 4 + rg) * 128 + nl] = f2bf(v);
            }
    }
    __syncthreads();
    unsigned short* C = (unsigned short*)Cp;
    #pragma unroll
    for (int c = 0; c < 8; ++c) {
        int idx = tid + c * 256;
        int r = idx >> 4, ch = idx & 15;
        if (m0 + r < M)
            *reinterpret_cast<ushort8v*>(C + (size_t)(m0 + r) * ldc + n0 + ch * 8) =
                *reinterpret_cast<const ushort8v*>(&smem[r * 128 + ch * 8]);
    }
}

// ------------------------------------------------------- windowed attention (bf16 qkv)
template<int CAPT, int HG>
__global__ __launch_bounds__(256) void attn_kernel(
    const unsigned short* __restrict__ qkv, const int* __restrict__ vlist, int nvox,
    unsigned short* __restrict__ oout)
{
    __shared__ float Ks[CAPT][HG * 16];
    __shared__ float Vs[CAPT][HG * 16];
    __shared__ int vl[CAPT];
    const int w = blockIdx.x;
    const int hb = blockIdx.y * HG;
    const int tid = threadIdx.x;
    const int T = min(CAPT, nvox - w * CAPT);
    if (tid < T) vl[tid] = vlist[w * CAPT + tid];
    constexpr int R8 = HG * 2;
    for (int idx = tid; idx < T * R8; idx += 256) {
        int t = idx / R8, c8 = (idx % R8) * 8;
        int vox = vlist[w * CAPT + t];
        const unsigned short* base = qkv + (size_t)vox * 384 + hb * 16 + c8;
        ushort8v kv = *reinterpret_cast<const ushort8v*>(base + 128);
        ushort8v vv = *reinterpret_cast<const ushort8v*>(base + 256);
        #pragma unroll
        for (int q = 0; q < 8; ++q) { Ks[t][c8 + q] = bf2f(kv[q]); Vs[t][c8 + q] = bf2f(vv[q]); }
    }
    __syncthreads();
    const int ITEMS = T * HG;
    for (int item = tid; item < ITEMS; item += 256) {
        int h = item & (HG - 1);
        int q = item / HG;
        int vq = vl[q];
        const unsigned short* qb = qkv + (size_t)vq * 384 + (hb + h) * 16;
        ushort8v qa = *reinterpret_cast<const ushort8v*>(qb);
        ushort8v qc = *reinterpret_cast<const ushort8v*>(qb + 8);
        float4 q0 = make_float4(bf2f(qa[0]), bf2f(qa[1]), bf2f(qa[2]), bf2f(qa[3]));
        float4 q1 = make_float4(bf2f(qa[4]), bf2f(qa[5]), bf2f(qa[6]), bf2f(qa[7]));
        float4 q2 = make_float4(bf2f(qc[0]), bf2f(qc[1]), bf2f(qc[2]), bf2f(qc[3]));
        float4 q3 = make_float4(bf2f(qc[4]), bf2f(qc[5]), bf2f(qc[6]), bf2f(qc[7]));
        float mx = -INFINITY, l = 0.f;
        float4 o0 = make_float4(0,0,0,0), o1 = o0, o2 = o0, o3 = o0;
        for (int t = 0; t < T; ++t) {
            const float4* kr = reinterpret_cast<const float4*>(&Ks[t][h * 16]);
            float4 k0 = kr[0], k1 = kr[1], k2 = kr[2], k3 = kr[3];
            float s = q0.x*k0.x + q0.y*k0.y + q0.z*k0.z + q0.w*k0.w
                    + q1.x*k1.x + q1.y*k1.y + q1.z*k1.z + q1.w*k1.w
                    + q2.x*k2.x + q2.y*k2.y + q2.z*k2.z + q2.w*k2.w
                    + q3.x*k3.x + q3.y*k3.y + q3.z*k3.z + q3.w*k3.w;
            s *= 0.25f;
            float mo = mx;
            mx = fmaxf(mx, s);
            float cc = __expf(mo - mx);
            float p  = __expf(s - mx);
            l = l * cc + p;
            const float4* vr = reinterpret_cast<const float4*>(&Vs[t][h * 16]);
            float4 v0 = vr[0], v1 = vr[1], v2 = vr[2], v3 = vr[3];
            o0.x = o0.x*cc + p*v0.x; o0.y = o0.y*cc + p*v0.y; o0.z = o0.z*cc + p*v0.z; o0.w = o0.w*cc + p*v0.w;
            o1.x = o1.x*cc + p*v1.x; o1.y = o1.y*cc + p*v1.y; o1.z = o1.z*cc + p*v1.z; o1.w = o1.w*cc + p*v1.w;
            o2.x = o2.x*cc + p*v2.x; o2.y = o2.y*cc + p*v2.y; o2.z = o2.z*cc + p*v2.z; o2.w = o2.w*cc + p*v2.w;
            o3.x = o3.x*cc + p*v3.x; o3.y = o3.y*cc + p*v3.y; o3.z = o3.z*cc + p*v3.z; o3.w = o3.w*cc + p*v3.w;
        }
        float rl = 1.0f / l;
        ushort8v r0, r1;
        r0[0]=f2bf(o0.x*rl); r0[1]=f2bf(o0.y*rl); r0[2]=f2bf(o0.z*rl); r0[3]=f2bf(o0.w*rl);
        r0[4]=f2bf(o1.x*rl); r0[5]=f2bf(o1.y*rl); r0[6]=f2bf(o1.z*rl); r0[7]=f2bf(o1.w*rl);
        r1[0]=f2bf(o2.x*rl); r1[1]=f2bf(o2.y*rl); r1[2]=f2bf(o2.z*rl); r1[3]=f2bf(o2.w*rl);
        r1[4]=f2bf(o3.x*rl); r1[5]=f2bf(o3.y*rl); r1[6]=f2bf(o3.z*rl); r1[7]=f2bf(o3.w*rl);
        unsigned short* op = oout + (size_t)vq * 128 + (hb + h) * 16;
        *reinterpret_cast<ushort8v*>(op) = r0;
        *reinterpret_cast<ushort8v*>(op + 8) = r1;
    }
}

// ------------------- fused tail: out-proj + LN1 + FFN1(GELU) + FFN2 + LN2
// Block = 64 rows, 4 waves. Single LDS arena; all global row indices clamped < M.
__global__ __launch_bounds__(256) void fused_tail(
    const unsigned short* __restrict__ obuf,
    const unsigned short* __restrict__ oww,
    const float* __restrict__ obp,
    const unsigned short* __restrict__ w1,
    const float* __restrict__ b1p,
    const unsigned short* __restrict__ w2,
    const float* __restrict__ b2p,
    const float* __restrict__ lng1, const float* __restrict__ lnb1,
    const float* __restrict__ lng2, const float* __restrict__ lnb2,
    float* __restrict__ feat, unsigned short* __restrict__ featb, int M)
{
    __shared__ unsigned short S[36864];      // A[0,4096) W[4096,12288) X[12288,20480) H[20480,36864)
    __shared__ float2 lnsum[64][4];
    unsigned short* Abuf = S;
    unsigned short* Wbuf = S + 4096;
    unsigned short* Xbuf = S + 12288;
    unsigned short* Hbuf = S + 20480;
    const int tid = threadIdx.x;
    const int lane = tid & 63, wave = tid >> 6;
    const int llo = lane & 15, lhi = lane >> 4;
    const int r8 = lane >> 3, c8 = lane & 7;
    const int m0 = blockIdx.x * 64;

    auto stageA = [&](int k0) {              // 64 rows of obuf, row-clamped
        #pragma unroll
        for (int it = 0; it < 2; ++it) {
            int rb = wave * 16 + it * 8;
            int r = rb + r8;
            int gm = m0 + r; if (gm >= M) gm = M - 1;
            gll16(obuf + (size_t)gm * 128 + k0 * 64 + ((c8 ^ (r & 7)) * 8), Abuf + rb * 64);
        }
    };
    auto stageW = [&](const unsigned short* src, int ldk, int koff) {   // 128 rows
        #pragma unroll
        for (int it = 0; it < 4; ++it) {
            int rb = wave * 32 + it * 8;
            int r = rb + r8;
            gll16(src + (size_t)r * ldk + koff + ((c8 ^ (r & 7)) * 8), Wbuf + rb * 64);
        }
    };
    auto frag = [&](const unsigned short* buf, int r, int kk) {
        return *reinterpret_cast<const short8v*>(
            (const char*)buf + r * 128 + (((kk * 4 + lhi) ^ (r & 7)) * 16));
    };
    auto sput = [&](unsigned short* buf, int col, int r, float v) {
        int slab = col >> 6, k = col & 63;
        buf[slab * 4096 + r * 64 + (((k >> 3) ^ (r & 7)) * 8) + (k & 7)] = f2bf(v);
    };

    // ================= phase 1: out-proj (M=64, N=128, K=128) =================
    f32x4 acc0[4][2] = {};
    #pragma unroll
    for (int k0 = 0; k0 < 2; ++k0) {
        stageA(k0);
        stageW(oww, 128, k0 * 64);
        __syncthreads();
        #pragma unroll
        for (int kk = 0; kk < 2; ++kk) {
            short8v a[4], w[2];
            #pragma unroll
            for (int i = 0; i < 4; ++i) a[i] = frag(Abuf, i * 16 + llo, kk);
            #pragma unroll
            for (int j = 0; j < 2; ++j) w[j] = frag(Wbuf, wave * 32 + j * 16 + llo, kk);
            #pragma unroll
            for (int i = 0; i < 4; ++i)
                #pragma unroll
                for (int j = 0; j < 2; ++j)
                    acc0[i][j] = __builtin_amdgcn_mfma_f32_16x16x32_bf16(a[i], w[j], acc0[i][j], 0, 0, 0);
        }
        __syncthreads();
    }

    // ================= LN1 (residual from feat f32, row-clamped) =================
    {
        float ob0 = obp[wave * 32 + llo];
        float ob1 = obp[wave * 32 + 16 + llo];
        #pragma unroll
        for (int i = 0; i < 4; ++i)
            #pragma unroll
            for (int rg = 0; rg < 4; ++rg) {
                int m = m0 + i * 16 + lhi * 4 + rg;
                if (m >= M) m = M - 1;
                const float* fp = feat + (size_t)m * 128 + wave * 32 + llo;
                float x0 = fp[0]  + acc0[i][0][rg] + ob0;
                float x1 = fp[16] + acc0[i][1][rg] + ob1;
                acc0[i][0][rg] = x0; acc0[i][1][rg] = x1;
                float s1 = x0 + x1, s2 = x0 * x0 + x1 * x1;
                #pragma unroll
                for (int off = 1; off < 16; off <<= 1) {
                    s1 += __shfl_xor(s1, off);
                    s2 += __shfl_xor(s2, off);
                }
                if (llo == 0) lnsum[i * 16 + lhi * 4 + rg][wave] = make_float2(s1, s2);
            }
    }
    __syncthreads();
    {
        float gg0 = lng1[wave * 32 + llo],      bb0 = lnb1[wave * 32 + llo];
        float gg1 = lng1[wave * 32 + 16 + llo], bb1 = lnb1[wave * 32 + 16 + llo];
        #pragma unroll
        for (int i = 0; i < 4; ++i)
            #pragma unroll
            for (int rg = 0; rg < 4; ++rg) {
                int r = i * 16 + lhi * 4 + rg;
                float2 t0 = lnsum[r][0], t1 = lnsum[r][1], t2 = lnsum[r][2], t3 = lnsum[r][3];
                float mu = (t0.x + t1.x + t2.x + t3.x) * 0.0078125f;
                float var = fmaxf((t0.y + t1.y + t2.y + t3.y) * 0.0078125f - mu * mu, 0.f);
                float inv = rsqrtf(var + 1e-5f);
                float x0 = (acc0[i][0][rg] - mu) * inv * gg0 + bb0;
                float x1 = (acc0[i][1][rg] - mu) * inv * gg1 + bb1;
                acc0[i][0][rg] = x0; acc0[i][1][rg] = x1;   // keep: residual for LN2
                sput(Xbuf, wave * 32 + llo, r, x0);
                sput(Xbuf, wave * 32 + 16 + llo, r, x1);
            }
    }
    __syncthreads();   // Xbuf fully visible

    // ================= phase 2: FFN1 (N=256 in 2 halves, K=128) =================
    f32x4 acc1[4][4] = {};
    #pragma unroll
    for (int nh = 0; nh < 2; ++nh)
        #pragma unroll
        for (int k0 = 0; k0 < 2; ++k0) {
            stageW(w1 + (size_t)nh * 16384, 128, k0 * 64);
            __syncthreads();
            #pragma unroll
            for (int kk = 0; kk < 2; ++kk) {
                short8v a[4], w[2];
                #pragma unroll
                for (int i = 0; i < 4; ++i) a[i] = frag(Xbuf + k0 * 4096, i * 16 + llo, kk);
                #pragma unroll
                for (int j = 0; j < 2; ++j) w[j] = frag(Wbuf, wave * 32 + j * 16 + llo, kk);
                #pragma unroll
                for (int i = 0; i < 4; ++i)
                    #pragma unroll
                    for (int j = 0; j < 2; ++j)
                        acc1[i][nh * 2 + j] = __builtin_amdgcn_mfma_f32_16x16x32_bf16(
                            a[i], w[j], acc1[i][nh * 2 + j], 0, 0, 0);
            }
            __syncthreads();
        }

    // ================= GELU -> Hbuf =================
    {
        float bb[4];
        #pragma unroll
        for (int c = 0; c < 4; ++c)
            bb[c] = b1p[(c >> 1) * 128 + wave * 32 + (c & 1) * 16 + llo];
        #pragma unroll
        for (int i = 0; i < 4; ++i)
            #pragma unroll
            for (int c = 0; c < 4; ++c) {
                int col = (c >> 1) * 128 + wave * 32 + (c & 1) * 16 + llo;
                #pragma unroll
                for (int rg = 0; rg < 4; ++rg) {
                    float v = acc1[i][c][rg] + bb[c];
                    v = 0.5f * v * (1.0f + erff(v * 0.7071067811865475f));
                    sput(Hbuf, col, i * 16 + lhi * 4 + rg, v);
                }
            }
    }
    __syncthreads();   // Hbuf fully visible

    // ================= phase 3: FFN2 (N=128, K=256) =================
    f32x4 acc2[4][2] = {};
    #pragma unroll
    for (int k0 = 0; k0 < 4; ++k0) {
        stageW(w2, 256, k0 * 64);
        __syncthreads();
        #pragma unroll
        for (int kk = 0; kk < 2; ++kk) {
            short8v a[4], w[2];
            #pragma unroll
            for (int i = 0; i < 4; ++i) a[i] = frag(Hbuf + k0 * 4096, i * 16 + llo, kk);
            #pragma unroll
            for (int j = 0; j < 2; ++j) w[j] = frag(Wbuf, wave * 32 + j * 16 + llo, kk);
            #pragma unroll
            for (int i = 0; i < 4; ++i)
                #pragma unroll
                for (int j = 0; j < 2; ++j)
                    acc2[i][j] = __builtin_amdgcn_mfma_f32_16x16x32_bf16(a[i], w[j], acc2[i][j], 0, 0, 0);
        }
        __syncthreads();
    }

    // ================= LN2 (residual = post-LN1 x held in acc0) =================
    {
        float b20 = b2p[wave * 32 + llo];
        float b21 = b2p[wave * 32 + 16 + llo];
        #pragma unroll
        for (int i = 0; i < 4; ++i)
            #pragma unroll
            for (int rg = 0; rg < 4; ++rg) {
                float x0 = acc0[i][0][rg] + acc2[i][0][rg] + b20;
                float x1 = acc0[i][1][rg] + acc2[i][1][rg] + b21;
                acc2[i][0][rg] = x0; acc2[i][1][rg] = x1;
                float s1 = x0 + x1, s2 = x0 * x0 + x1 * x1;
                #pragma unroll
                for (int off = 1; off < 16; off <<= 1) {
                    s1 += __shfl_xor(s1, off);
                    s2 += __shfl_xor(s2, off);
                }
                if (llo == 0) lnsum[i * 16 + lhi * 4 + rg][wave] = make_float2(s1, s2);
            }
    }
    __syncthreads();
    {
        float gg0 = lng2[wave * 32 + llo],      bb0 = lnb2[wave * 32 + llo];
        float gg1 = lng2[wave * 32 + 16 + llo], bb1 = lnb2[wave * 32 + 16 + llo];
        #pragma unroll
        for (int i = 0; i < 4; ++i)
            #pragma unroll
            for (int rg = 0; rg < 4; ++rg) {
                int r = i * 16 + lhi * 4 + rg;
                int m = m0 + r;
                if (m >= M) continue;
                float2 t0 = lnsum[r][0], t1 = lnsum[r][1], t2 = lnsum[r][2], t3 = lnsum[r][3];
                float mu = (t0.x + t1.x + t2.x + t3.x) * 0.0078125f;
                float var = fmaxf((t0.y + t1.y + t2.y + t3.y) * 0.0078125f - mu * mu, 0.f);
                float inv = rsqrtf(var + 1e-5f);
                float v0 = (acc2[i][0][rg] - mu) * inv * gg0 + bb0;
                float v1 = (acc2[i][1][rg] - mu) * inv * gg1 + bb1;
                size_t base = (size_t)m * 128 + wave * 32 + llo;
                feat[base] = v0;       feat[base + 16] = v1;
                featb[base] = f2bf(v0); featb[base + 16] = f2bf(v1);
            }
    }
}

// ------------------- BEV scatter into padded canvas (bf16, stride 420)
__global__ __launch_bounds__(256) void scatter_kernel(const float* __restrict__ feat,
    const int* __restrict__ coors, unsigned short* __restrict__ canvas)
{
    int idx = blockIdx.x * 256 + threadIdx.x;
    if (idx >= NVOX * 16) return;
    int n = idx >> 4, c8 = (idx & 15) << 3;
    int b = coors[n * 4], y = coors[n * 4 + 2], x = coors[n * 4 + 3];
    const float* src = feat + (size_t)n * 128 + c8;
    float4 u0 = *reinterpret_cast<const float4*>(src);
    float4 u1 = *reinterpret_cast<const float4*>(src + 4);
    ushort8v v;
    v[0]=f2bf(u0.x); v[1]=f2bf(u0.y); v[2]=f2bf(u0.z); v[3]=f2bf(u0.w);
    v[4]=f2bf(u1.x); v[5]=f2bf(u1.y); v[6]=f2bf(u1.z); v[7]=f2bf(u1.w);
    size_t p = (((size_t)b * 404 + y + 2) * 420 + x + 2) * 128 + c8;
    *reinterpret_cast<ushort8v*>(canvas + p) = v;
}

// --------- zero the halo of a stride-420 padded canvas
__global__ __launch_bounds__(256) void halo_zero(unsigned short* __restrict__ c) {
    int idx = blockIdx.x * 256 + threadIdx.x;
    if (idx >= 2 * 9680 * 16) return;
    int b = idx / (9680 * 16);
    int rem = idx % (9680 * 16);
    int p = rem >> 4, ch = (rem & 15) * 8;
    int y, x;
    if (p < 1680) { int ry = p / 420; y = (ry < 2) ? ry : ry + 400; x = p % 420; }
    else { int q = p - 1680; y = 2 + q / 20; int cx = q % 20; x = (cx < 2) ? cx : cx + 400; }
    ushort8v z = {};
    *reinterpret_cast<ushort8v*>(c + (((size_t)b * 404 + y) * 420 + x) * 128 + ch) = z;
}

// ------------------- conv weight re-layout -> bf16 [i][ky*3+kx][cout][cin]
__global__ __launch_bounds__(256) void wtrans_kernel(const float* __restrict__ cw,
                                                     unsigned short* __restrict__ wbuf)
{
    int idx = blockIdx.x * 256 + threadIdx.x;
    if (idx >= 2 * 9 * 128 * 128) return;
    int ci = idx & 127;
    int co = (idx >> 7) & 127;
    int kk = (idx >> 14) % 9;
    int i  = idx / (9 * 16384);
    wbuf[idx] = f2bf(cw[(((size_t)i * 128 + co) * 128 + ci) * 9 + kk]);
}

// ---------------- 3x3 dilated(2) conv + BN + ReLU, LDS-A once + LDS-W double-buffered
template<bool NCHW_OUT>
__global__ __launch_bounds__(512, 1) void conv_mfma(
    const unsigned short* __restrict__ in, const unsigned short* __restrict__ wbuf,
    const float* __restrict__ g, const float* __restrict__ bsh,
    const float* __restrict__ bm, const float* __restrict__ bv,
    void* __restrict__ out)
{
    __shared__ unsigned short Ab[8 * 36 * 128];
    __shared__ unsigned short Wb[2 * 128 * 128];
    const int tid = threadIdx.x;
    const int lane = tid & 63, wave = tid >> 6;
    const int cog = wave & 1, yg = wave >> 1;
    const int llo = lane & 15, lhi = lane >> 4;
    const int x0 = blockIdx.x * 32, y0 = blockIdx.y * 4, b = blockIdx.z;
    const int c16s = lane & 15;

    #pragma unroll
    for (int it = 0; it < 9; ++it) {
        int gidx = it * 32 + wave * 4 + lhi;
        int row = gidx / 36, xi = gidx % 36;
        gll16(in + (((size_t)b * 404 + y0 + row) * 420 + x0 + xi) * 128 + ((c16s ^ (xi & 15)) * 8),
              Ab + (size_t)(it * 512 + wave * 64) * 8);
    }
    {
        const unsigned short* wt = wbuf;
        #pragma unroll
        for (int it = 0; it < 4; ++it) {
            int co = it * 32 + wave * 4 + lhi;
            gll16(wt + co * 128 + ((c16s ^ (co & 15)) * 8),
                  Wb + (size_t)(it * 512 + wave * 64) * 8);
        }
    }
    __syncthreads();

    f32x4 acc[2][4] = {};
    #pragma unroll
    for (int t = 0; t < 9; ++t) {
        if (t < 8) {
            const unsigned short* wt = wbuf + (size_t)(t + 1) * 16384;
            unsigned short* dst = Wb + ((t + 1) & 1) * 16384;
            #pragma unroll
            for (int it = 0; it < 4; ++it) {
                int co = it * 32 + wave * 4 + lhi;
                gll16(wt + co * 128 + ((c16s ^ (co & 15)) * 8),
                      dst + (size_t)(it * 512 + wave * 64) * 8);
            }
        }
        const unsigned short* Wp = Wb + (t & 1) * 16384;
        const int ky = t / 3, kx = t % 3;
        const int r = yg + 2 * ky;
        #pragma unroll
        for (int kk = 0; kk < 4; ++kk) {
            short8v a[2], w[4];
            #pragma unroll
            for (int i = 0; i < 2; ++i) {
                int xi = i * 16 + llo + 2 * kx;
                a[i] = *reinterpret_cast<const short8v*>(
                    (const char*)Ab + (r * 36 + xi) * 256 + ((kk * 64 + lhi * 16) ^ ((xi & 15) << 4)));
            }
            #pragma unroll
            for (int j = 0; j < 4; ++j) {
                int co = cog * 64 + j * 16 + llo;
                w[j] = *reinterpret_cast<const short8v*>(
                    (const char*)Wp + co * 256 + ((kk * 64 + lhi * 16) ^ ((co & 15) << 4)));
            }
            #pragma unroll
            for (int i = 0; i < 2; ++i)
                #pragma unroll
                for (int j = 0; j < 4; ++j)
                    acc[i][j] = __builtin_amdgcn_mfma_f32_16x16x32_bf16(a[i], w[j], acc[i][j], 0, 0, 0);
        }
        __syncthreads();
    }

    const int y = y0 + yg;
    if (NCHW_OUT) {
        #pragma unroll
        for (int j = 0; j < 4; ++j) {
            int co = cog * 64 + j * 16 + llo;
            float scale = rsqrtf(bv[co] + 1e-3f) * g[co];
            float shift = bsh[co] - bm[co] * scale;
            #pragma unroll
            for (int i = 0; i < 2; ++i) {
                int px = x0 + i * 16 + lhi * 4;
                if (px < 400) {
                    float4 v;
                    v.x = fmaxf(acc[i][j][0] * scale + shift, 0.f);
                    v.y = fmaxf(acc[i][j][1] * scale + shift, 0.f);
                    v.z = fmaxf(acc[i][j][2] * scale + shift, 0.f);
                    v.w = fmaxf(acc[i][j][3] * scale + shift, 0.f);
                    *reinterpret_cast<float4*>(
                        (float*)out + (((size_t)b * 128 + co) * 400 + y) * 400 + px) = v;
                }
            }
        }
    } else {
        unsigned short* Cw = Wb + wave * 2048;
        #pragma unroll
        for (int j = 0; j < 4; ++j) {
            int co = cog * 64 + j * 16 + llo;
            float scale = rsqrtf(bv[co] + 1e-3f) * g[co];
            float shift = bsh[co] - bm[co] * scale;
            #pragma unroll
            for (int i = 0; i < 2; ++i)
                #pragma unroll
                for (int rg = 0; rg < 4; ++rg)
                    Cw[(i * 16 + lhi * 4 + rg) * 64 + j * 16 + llo] =
                        f2bf(fmaxf(acc[i][j][rg] * scale + shift, 0.f));
        }
        #pragma unroll
        for (int s = 0; s < 4; ++s) {
            int pxl = s * 8 + (lane >> 3);
            int oct = lane & 7;
            int px = x0 + pxl;
            if (px < 400)
                *reinterpret_cast<ushort8v*>(
                    (unsigned short*)out + (((size_t)b * 404 + y + 2) * 420 + px + 2) * 128
                                         + cog * 64 + oct * 8) =
                    *reinterpret_cast<const ushort8v*>(&Cw[pxl * 64 + oct * 8]);
        }
    }
}

// ---------------------------------------------------------------- launcher
extern "C" void kernel_launch(void* const* d_in, const int* in_sizes, int n_in,
                              void* d_out, int out_size, void* d_ws, size_t ws_size,
                              hipStream_t stream) {
    const float* voxel_feat = (const float*)d_in[0];
    const int*   coors      = (const int*)d_in[1];
    const float* ciw0       = (const float*)d_in[2];
    const float* ciw1       = (const float*)d_in[3];
    const int* vx[2][2] = {{(const int*)d_in[4], (const int*)d_in[6]},
                           {(const int*)d_in[8], (const int*)d_in[10]}};
    const float* ipw = (const float*)d_in[12];
    const float* ipb = (const float*)d_in[13];
    const float* ow  = (const float*)d_in[14];
    const float* obp = (const float*)d_in[15];
    const float* l1w = (const float*)d_in[16];
    const float* l1b = (const float*)d_in[17];
    const float* l2w = (const float*)d_in[18];
    const float* l2b = (const float*)d_in[19];
    const float* g1  = (const float*)d_in[20];
    const float* b1  = (const float*)d_in[21];
    const float* g2  = (const float*)d_in[22];
    const float* b2  = (const float*)d_in[23];
    const float* cw  = (const float*)d_in[24];
    const float* bng = (const float*)d_in[25];
    const float* bnb = (const float*)d_in[26];
    const float* bnm = (const float*)d_in[27];
    const float* bnv = (const float*)d_in[28];

    float* F = (float*)d_ws;
    unsigned short* W0   = (unsigned short*)F;
    unsigned short* ipwb = W0;                           // 589824
    unsigned short* owb  = W0 + 589824;                  // 196608
    unsigned short* l1wb = W0 + 786432;                  // 393216
    unsigned short* l2wb = W0 + 1179648;                 // 393216
    unsigned short* cwb  = W0 + 1572864;                 // 294912
    float* feat = F + 940000;                            // 7.68M f32
    unsigned short* featb = (unsigned short*)(F + 8620000);
    unsigned short* pos0  = (unsigned short*)(F + 12460000);
    unsigned short* pos1  = (unsigned short*)(F + 16300000);
    unsigned short* obufb = (unsigned short*)(F + 20140000);
    unsigned short* canvas1 = (unsigned short*)(F + 8620000);
    unsigned short* canvas2 = (unsigned short*)(F + 30339040);
    unsigned short* qkvb = (unsigned short*)d_out;

    feat_init<<<30000, 256, 0, stream>>>(voxel_feat, feat, featb);
    pos_kernel<<<30000, 256, 0, stream>>>(ciw0, pos0);
    pos_kernel<<<30000, 256, 0, stream>>>(ciw1, pos1);
    cvt_bf16<<<(589824 + 255) / 256, 256, 0, stream>>>(ipw, ipwb, 589824);
    cvt_bf16<<<(196608 + 255) / 256, 256, 0, stream>>>(ow,  owb,  196608);
    cvt_bf16<<<(393216 + 255) / 256, 256, 0, stream>>>(l1w, l1wb, 393216);
    cvt_bf16<<<(393216 + 255) / 256, 256, 0, stream>>>(l2w, l2wb, 393216);
    wtrans_kernel<<<(2 * 9 * 16384 + 255) / 256, 256, 0, stream>>>(cw, cwb);

    for (int li = 0; li < 12; ++li) {
        int s = li & 1;
        const unsigned short* pos = s ? pos1 : pos0;
        gemm_mfma<128, true, false, true, false><<<dim3(469, 3), 256, 0, stream>>>(
            featb, pos, 2, ipwb + (size_t)li * 49152, ipb + li * 384, qkvb, NVOX, 384);
        attn_kernel<25, 8><<<dim3(960, 1), 256, 0, stream>>>(qkvb, vx[s][0], 24000, obufb);
        attn_kernel<100, 2><<<dim3(360, 4), 256, 0, stream>>>(qkvb, vx[s][1], 36000, obufb);
        fused_tail<<<938, 256, 0, stream>>>(
            obufb, owb + (size_t)li * 16384, obp + li * 128,
            l1wb + (size_t)li * 32768, l1b + li * 256,
            l2wb + (size_t)li * 32768, l2b + li * 128,
            g1 + li * 128, b1 + li * 128, g2 + li * 128, b2 + li * 128,
            feat, featb, NVOX);
    }

    hipMemsetAsync(canvas1, 0, (size_t)43438080 * 2, stream);
    halo_zero<<<(2 * 9680 * 16 + 255) / 256, 256, 0, stream>>>(canvas2);
    scatter_kernel<<<(NVOX * 16 + 255) / 256, 256, 0, stream>>>(feat, coors, canvas1);
    conv_mfma<false><<<dim3(13, 100, 2), 512, 0, stream>>>(
        canvas1, cwb, bng, bnb, bnm, bnv, canvas2);
    conv_mfma<true><<<dim3(13, 100, 2), 512, 0, stream>>>(
        canvas2, cwb + 9 * 16384, bng + 128, bnb + 128, bnm + 128, bnv + 128, (float*)d_out);
}

// Round 10
// 2708.634 us; speedup vs baseline: 1.0224x; 1.0224x over previous
//
#include <hip/hip_runtime.h>
#include <math.h>

#define NVOX 60000

typedef __attribute__((ext_vector_type(8))) short short8v;            // 8 bf16 raw
typedef __attribute__((ext_vector_type(8))) unsigned short ushort8v;  // 8 bf16 raw
typedef __attribute__((ext_vector_type(4))) float f32x4;

static __device__ __forceinline__ unsigned short f2bf(float f) {
    unsigned u = __float_as_uint(f);
    unsigned r = (u + 0x7fffu + ((u >> 16) & 1u)) >> 16;
    return (unsigned short)r;
}
static __device__ __forceinline__ float bf2f(unsigned short h) {
    return __uint_as_float(((unsigned)h) << 16);
}
// async global->LDS 16B per lane: dest = lds_base + lane*16 (wave-uniform base)
static __device__ __forceinline__ void gll16(const unsigned short* g, unsigned short* l) {
    __builtin_amdgcn_global_load_lds(
        (const __attribute__((address_space(1))) unsigned*)g,
        (__attribute__((address_space(3))) unsigned*)l,
        16, 0, 0);
}

// ---------------------------------------------------------------- pos embed (bf16 out)
__global__ __launch_bounds__(256) void pos_kernel(const float* __restrict__ ciw,
                                                  unsigned short* __restrict__ pos) {
    int idx = blockIdx.x * 256 + threadIdx.x;
    if (idx >= NVOX * 128) return;
    int n = idx >> 7, d = idx & 127;
    int c = d >> 6, t = (d & 63) >> 1;
    float xy = ciw[n * 2 + c] - 6.0f;
    float inv = exp2f((float)t * (13.287712379549449f / 32.0f)); // 10000^(t/32)
    float e = xy / inv;
    pos[idx] = f2bf((d & 1) ? cosf(e) : sinf(e));
}

// ------------------------------------------------------- fp32 -> bf16 convert
__global__ __launch_bounds__(256) void cvt_bf16(const float* __restrict__ in,
                                                unsigned short* __restrict__ out, int n) {
    int idx = blockIdx.x * 256 + threadIdx.x;
    if (idx < n) out[idx] = f2bf(in[idx]);
}

// -------------------------------------------- feat init: f32 copy + bf16 shadow
__global__ __launch_bounds__(256) void feat_init(const float* __restrict__ vf,
                                                 float* __restrict__ feat,
                                                 unsigned short* __restrict__ featb) {
    int idx = blockIdx.x * 256 + threadIdx.x;
    if (idx >= NVOX * 128) return;
    float v = vf[idx];
    feat[idx] = v;
    featb[idx] = f2bf(v);
}

// ----------------------------------------- MFMA GEMM (QKV): C = (A(+pos))*W^T + b
template<int KTOT, bool ADD, bool GELU, bool CBF16, bool LNF>
__global__ __launch_bounds__(256) void gemm_mfma(
    const unsigned short* __restrict__ A, const unsigned short* __restrict__ Aadd, int add_nblk,
    const unsigned short* __restrict__ W, const float* __restrict__ bias,
    void* __restrict__ Cp, int M, int ldc)
{
    __shared__ unsigned short smem[128 * 128];   // As(16KB) + Ws(16KB), reused as Cs(32KB)
    unsigned short* As = smem;
    unsigned short* Ws = smem + 128 * 64;
    const int tid = threadIdx.x;
    const int lane = tid & 63, wave = tid >> 6;
    const int wr = wave >> 1, wc = wave & 1;
    const int llo = lane & 15, lhi = lane >> 4;
    const int m0 = blockIdx.x * 128;
    const int n0 = blockIdx.y * 128;
    const bool addp = ADD && ((int)blockIdx.y < add_nblk);
    const int gr = lane >> 3;           // row within 8-row group
    const int gc = (lane & 7) ^ gr;     // pre-swizzled source chunk
    f32x4 acc[4][4] = {};

    for (int k0 = 0; k0 < KTOT; k0 += 64) {
        #pragma unroll
        for (int p = 0; p < 4; ++p) {
            int r0 = wave * 32 + p * 8;
            gll16(W + (size_t)(n0 + r0 + gr) * KTOT + k0 + gc * 8, &Ws[r0 * 64]);
        }
        if (!addp) {
            #pragma unroll
            for (int p = 0; p < 4; ++p) {
                int r0 = wave * 32 + p * 8;
                gll16(A + (size_t)(m0 + r0 + gr) * KTOT + k0 + gc * 8, &As[r0 * 64]);
            }
        } else {
            #pragma unroll
            for (int p = 0; p < 4; ++p) {
                int c = tid + p * 256;
                int r = c >> 3, c16 = c & 7;
                int m = m0 + r;
                short8v av = {};
                if (m < M) {
                    ushort8v fa = *reinterpret_cast<const ushort8v*>(A + (size_t)m * KTOT + k0 + c16 * 8);
                    ushort8v pa = *reinterpret_cast<const ushort8v*>(Aadd + (size_t)m * 128 + k0 + c16 * 8);
                    #pragma unroll
                    for (int q = 0; q < 8; ++q) av[q] = (short)f2bf(bf2f(fa[q]) + bf2f(pa[q]));
                }
                *reinterpret_cast<short8v*>((char*)As + r * 128 + ((c16 * 16) ^ ((r & 7) << 4))) = av;
            }
        }
        __syncthreads();
        #pragma unroll
        for (int kk = 0; kk < 2; ++kk) {
            int kb = kk * 64 + lhi * 16;
            short8v af[4], bf[4];
            #pragma unroll
            for (int i = 0; i < 4; ++i) {
                int r = wr * 64 + i * 16 + llo;
                af[i] = *reinterpret_cast<const short8v*>((const char*)As + r * 128 + (kb ^ ((r & 7) << 4)));
                int cc = wc * 64 + i * 16 + llo;
                bf[i] = *reinterpret_cast<const short8v*>((const char*)Ws + cc * 128 + (kb ^ ((cc & 7) << 4)));
            }
            #pragma unroll
            for (int i = 0; i < 4; ++i)
                #pragma unroll
                for (int j = 0; j < 4; ++j)
                    acc[i][j] = __builtin_amdgcn_mfma_f32_16x16x32_bf16(af[i], bf[j], acc[i][j], 0, 0, 0);
        }
        __syncthreads();
    }

    #pragma unroll
    for (int j = 0; j < 4; ++j) {
        int nl = wc * 64 + j * 16 + llo;
        float bn = bias[n0 + nl];
        #pragma unroll
        for (int i = 0; i < 4; ++i)
            #pragma unroll
            for (int rg = 0; rg < 4; ++rg) {
                float v = acc[i][j][rg] + bn;
                if (GELU) v = 0.5f * v * (1.0f + erff(v * 0.7071067811865475f));
                smem[(wr * 64 + i * 16 + lhi * 4 + rg) * 128 + nl] = f2bf(v);
            }
    }
    __syncthreads();
    unsigned short* C = (unsigned short*)Cp;
    #pragma unroll
    for (int c = 0; c < 8; ++c) {
        int idx = tid + c * 256;
        int r = idx >> 4, ch = idx & 15;
        if (m0 + r < M)
            *reinterpret_cast<ushort8v*>(C + (size_t)(m0 + r) * ldc + n0 + ch * 8) =
                *reinterpret_cast<const ushort8v*>(&smem[r * 128 + ch * 8]);
    }
}

// ------------------------------------------------------- windowed attention (bf16 qkv)
template<int CAPT, int HG>
__global__ __launch_bounds__(256) void attn_kernel(
    const unsigned short* __restrict__ qkv, const int* __restrict__ vlist, int nvox,
    unsigned short* __restrict__ oout)
{
    __shared__ float Ks[CAPT][HG * 16];
    __shared__ float Vs[CAPT][HG * 16];
    __shared__ int vl[CAPT];
    const int w = blockIdx.x;
    const int hb = blockIdx.y * HG;
    const int tid = threadIdx.x;
    const int T = min(CAPT, nvox - w * CAPT);
    if (tid < T) vl[tid] = vlist[w * CAPT + tid];
    constexpr int R8 = HG * 2;
    for (int idx = tid; idx < T * R8; idx += 256) {
        int t = idx / R8, c8 = (idx % R8) * 8;
        int vox = vlist[w * CAPT + t];
        const unsigned short* base = qkv + (size_t)vox * 384 + hb * 16 + c8;
        ushort8v kv = *reinterpret_cast<const ushort8v*>(base + 128);
        ushort8v vv = *reinterpret_cast<const ushort8v*>(base + 256);
        #pragma unroll
        for (int q = 0; q < 8; ++q) { Ks[t][c8 + q] = bf2f(kv[q]); Vs[t][c8 + q] = bf2f(vv[q]); }
    }
    __syncthreads();
    const int ITEMS = T * HG;
    for (int item = tid; item < ITEMS; item += 256) {
        int h = item & (HG - 1);
        int q = item / HG;
        int vq = vl[q];
        const unsigned short* qb = qkv + (size_t)vq * 384 + (hb + h) * 16;
        ushort8v qa = *reinterpret_cast<const ushort8v*>(qb);
        ushort8v qc = *reinterpret_cast<const ushort8v*>(qb + 8);
        float4 q0 = make_float4(bf2f(qa[0]), bf2f(qa[1]), bf2f(qa[2]), bf2f(qa[3]));
        float4 q1 = make_float4(bf2f(qa[4]), bf2f(qa[5]), bf2f(qa[6]), bf2f(qa[7]));
        float4 q2 = make_float4(bf2f(qc[0]), bf2f(qc[1]), bf2f(qc[2]), bf2f(qc[3]));
        float4 q3 = make_float4(bf2f(qc[4]), bf2f(qc[5]), bf2f(qc[6]), bf2f(qc[7]));
        float mx = -INFINITY, l = 0.f;
        float4 o0 = make_float4(0,0,0,0), o1 = o0, o2 = o0, o3 = o0;
        for (int t = 0; t < T; ++t) {
            const float4* kr = reinterpret_cast<const float4*>(&Ks[t][h * 16]);
            float4 k0 = kr[0], k1 = kr[1], k2 = kr[2], k3 = kr[3];
            float s = q0.x*k0.x + q0.y*k0.y + q0.z*k0.z + q0.w*k0.w
                    + q1.x*k1.x + q1.y*k1.y + q1.z*k1.z + q1.w*k1.w
                    + q2.x*k2.x + q2.y*k2.y + q2.z*k2.z + q2.w*k2.w
                    + q3.x*k3.x + q3.y*k3.y + q3.z*k3.z + q3.w*k3.w;
            s *= 0.25f;
            float mo = mx;
            mx = fmaxf(mx, s);
            float cc = __expf(mo - mx);
            float p  = __expf(s - mx);
            l = l * cc + p;
            const float4* vr = reinterpret_cast<const float4*>(&Vs[t][h * 16]);
            float4 v0 = vr[0], v1 = vr[1], v2 = vr[2], v3 = vr[3];
            o0.x = o0.x*cc + p*v0.x; o0.y = o0.y*cc + p*v0.y; o0.z = o0.z*cc + p*v0.z; o0.w = o0.w*cc + p*v0.w;
            o1.x = o1.x*cc + p*v1.x; o1.y = o1.y*cc + p*v1.y; o1.z = o1.z*cc + p*v1.z; o1.w = o1.w*cc + p*v1.w;
            o2.x = o2.x*cc + p*v2.x; o2.y = o2.y*cc + p*v2.y; o2.z = o2.z*cc + p*v2.z; o2.w = o2.w*cc + p*v2.w;
            o3.x = o3.x*cc + p*v3.x; o3.y = o3.y*cc + p*v3.y; o3.z = o3.z*cc + p*v3.z; o3.w = o3.w*cc + p*v3.w;
        }
        float rl = 1.0f / l;
        ushort8v r0, r1;
        r0[0]=f2bf(o0.x*rl); r0[1]=f2bf(o0.y*rl); r0[2]=f2bf(o0.z*rl); r0[3]=f2bf(o0.w*rl);
        r0[4]=f2bf(o1.x*rl); r0[5]=f2bf(o1.y*rl); r0[6]=f2bf(o1.z*rl); r0[7]=f2bf(o1.w*rl);
        r1[0]=f2bf(o2.x*rl); r1[1]=f2bf(o2.y*rl); r1[2]=f2bf(o2.z*rl); r1[3]=f2bf(o2.w*rl);
        r1[4]=f2bf(o3.x*rl); r1[5]=f2bf(o3.y*rl); r1[6]=f2bf(o3.z*rl); r1[7]=f2bf(o3.w*rl);
        unsigned short* op = oout + (size_t)vq * 128 + (hb + h) * 16;
        *reinterpret_cast<ushort8v*>(op) = r0;
        *reinterpret_cast<ushort8v*>(op + 8) = r1;
    }
}

// one 64xN=64 K=64 MFMA phase: acc[i][j] += A(64x64) x W(rows wave*32+j*16+llo)
static __device__ __forceinline__ void mma_phase(
    const unsigned short* Asl, const unsigned short* Wsl,
    f32x4 (&acc)[4][2], int llo, int lhi, int wave)
{
    #pragma unroll
    for (int kk = 0; kk < 2; ++kk) {
        short8v a[4], w[2];
        #pragma unroll
        for (int i = 0; i < 4; ++i) {
            int r = i * 16 + llo;
            a[i] = *reinterpret_cast<const short8v*>(
                (const char*)Asl + r * 128 + (((kk * 4 + lhi) ^ (r & 7)) * 16));
        }
        #pragma unroll
        for (int j = 0; j < 2; ++j) {
            int r = wave * 32 + j * 16 + llo;
            w[j] = *reinterpret_cast<const short8v*>(
                (const char*)Wsl + r * 128 + (((kk * 4 + lhi) ^ (r & 7)) * 16));
        }
        #pragma unroll
        for (int i = 0; i < 4; ++i)
            #pragma unroll
            for (int j = 0; j < 2; ++j)
                acc[i][j] = __builtin_amdgcn_mfma_f32_16x16x32_bf16(a[i], w[j], acc[i][j], 0, 0, 0);
    }
}

// ------------------- fused tail v2: out-proj + LN1 + FFN1(GELU) + FFN2 + LN2
// Pipelined: W slabs double-buffered (Wb0/Wb1), issue-next-during-compute.
// H chunked to 128 cols, unioned with dead A. LDS 64KB + lnsum -> 2 blocks/CU.
__global__ __launch_bounds__(256) void fused_tail(
    const unsigned short* __restrict__ obuf,
    const unsigned short* __restrict__ oww,
    const float* __restrict__ obp,
    const unsigned short* __restrict__ w1,
    const float* __restrict__ b1p,
    const unsigned short* __restrict__ w2,
    const float* __restrict__ b2p,
    const float* __restrict__ lng1, const float* __restrict__ lnb1,
    const float* __restrict__ lng2, const float* __restrict__ lnb2,
    float* __restrict__ feat, unsigned short* __restrict__ featb, int M)
{
    __shared__ unsigned short S[32768];   // Wb0[0,8192) Wb1[8192,16384) X[16384,24576) AH[24576,32768)
    __shared__ float2 lnsum[64][4];
    unsigned short* Wb0 = S;
    unsigned short* Wb1 = S + 8192;
    unsigned short* Xbuf = S + 16384;
    unsigned short* AH   = S + 24576;
    const int tid = threadIdx.x;
    const int lane = tid & 63, wave = tid >> 6;
    const int llo = lane & 15, lhi = lane >> 4;
    const int r8 = lane >> 3, c8 = lane & 7;
    const int m0 = blockIdx.x * 64;

    auto stageA = [&](int k0) {              // 64 rows of obuf slab k0 -> AH[k0]
        #pragma unroll
        for (int it = 0; it < 2; ++it) {
            int rb = wave * 16 + it * 8;
            int r = rb + r8;
            int gm = m0 + r; if (gm >= M) gm = M - 1;
            gll16(obuf + (size_t)gm * 128 + k0 * 64 + ((c8 ^ (r & 7)) * 8), AH + k0 * 4096 + rb * 64);
        }
    };
    auto stageW = [&](unsigned short* dst, const unsigned short* src, int ldk, int koff) {
        #pragma unroll
        for (int it = 0; it < 4; ++it) {
            int rb = wave * 32 + it * 8;
            int r = rb + r8;
            gll16(src + (size_t)r * ldk + koff + ((c8 ^ (r & 7)) * 8), dst + rb * 64);
        }
    };
    auto sput = [&](unsigned short* buf, int col, int r, float v) {   // col in [0,128)
        int slab = col >> 6, k = col & 63;
        buf[slab * 4096 + r * 64 + (((k >> 3) ^ (r & 7)) * 8) + (k & 7)] = f2bf(v);
    };

    f32x4 acc0[4][2] = {};
    f32x4 acc1a[4][2] = {};
    f32x4 acc1b[4][2] = {};
    f32x4 acc2[4][2] = {};

    // P1: stage A (both slabs) + ow.k0
    stageA(0); stageA(1);
    stageW(Wb0, oww, 128, 0);
    __syncthreads();
    // P2: compute OP.k0; issue ow.k1
    stageW(Wb1, oww, 128, 64);
    mma_phase(AH, Wb0, acc0, llo, lhi, wave);
    __syncthreads();
    // P3: compute OP.k1; issue w1.n0.k0
    stageW(Wb0, w1, 128, 0);
    mma_phase(AH + 4096, Wb1, acc0, llo, lhi, wave);
    __syncthreads();

    // P4: LN1 (residual from feat); issue w1.n0.k1
    stageW(Wb1, w1, 128, 64);
    {
        float ob0 = obp[wave * 32 + llo];
        float ob1 = obp[wave * 32 + 16 + llo];
        #pragma unroll
        for (int i = 0; i < 4; ++i)
            #pragma unroll
            for (int rg = 0; rg < 4; ++rg) {
                int m = m0 + i * 16 + lhi * 4 + rg;
                if (m >= M) m = M - 1;
                const float* fp = feat + (size_t)m * 128 + wave * 32 + llo;
                float x0 = fp[0]  + acc0[i][0][rg] + ob0;
                float x1 = fp[16] + acc0[i][1][rg] + ob1;
                acc0[i][0][rg] = x0; acc0[i][1][rg] = x1;
                float s1 = x0 + x1, s2 = x0 * x0 + x1 * x1;
                #pragma unroll
                for (int off = 1; off < 16; off <<= 1) {
                    s1 += __shfl_xor(s1, off);
                    s2 += __shfl_xor(s2, off);
                }
                if (llo == 0) lnsum[i * 16 + lhi * 4 + rg][wave] = make_float2(s1, s2);
            }
    }
    __syncthreads();
    {
        float gg0 = lng1[wave * 32 + llo],      bb0 = lnb1[wave * 32 + llo];
        float gg1 = lng1[wave * 32 + 16 + llo], bb1 = lnb1[wave * 32 + 16 + llo];
        #pragma unroll
        for (int i = 0; i < 4; ++i)
            #pragma unroll
            for (int rg = 0; rg < 4; ++rg) {
                int r = i * 16 + lhi * 4 + rg;
                float2 t0 = lnsum[r][0], t1 = lnsum[r][1], t2 = lnsum[r][2], t3 = lnsum[r][3];
                float mu = (t0.x + t1.x + t2.x + t3.x) * 0.0078125f;
                float var = fmaxf((t0.y + t1.y + t2.y + t3.y) * 0.0078125f - mu * mu, 0.f);
                float inv = rsqrtf(var + 1e-5f);
                float x0 = (acc0[i][0][rg] - mu) * inv * gg0 + bb0;
                float x1 = (acc0[i][1][rg] - mu) * inv * gg1 + bb1;
                acc0[i][0][rg] = x0; acc0[i][1][rg] = x1;   // residual for LN2
                sput(Xbuf, wave * 32 + llo, r, x0);
                sput(Xbuf, wave * 32 + 16 + llo, r, x1);
            }
    }
    __syncthreads();

    // P5: F1 n0.k0 (Wb0)
    mma_phase(Xbuf, Wb0, acc1a, llo, lhi, wave);
    __syncthreads();
    // P6: F1 n0.k1 (Wb1); issue w2.k0
    stageW(Wb0, w2, 256, 0);
    mma_phase(Xbuf + 4096, Wb1, acc1a, llo, lhi, wave);
    __syncthreads();
    // P7: GELU n0 -> AH; issue w2.k1
    stageW(Wb1, w2, 256, 64);
    {
        float bb0 = b1p[wave * 32 + llo];
        float bb1 = b1p[wave * 32 + 16 + llo];
        #pragma unroll
        for (int i = 0; i < 4; ++i)
            #pragma unroll
            for (int rg = 0; rg < 4; ++rg) {
                int r = i * 16 + lhi * 4 + rg;
                float v0 = acc1a[i][0][rg] + bb0;
                v0 = 0.5f * v0 * (1.0f + erff(v0 * 0.7071067811865475f));
                sput(AH, wave * 32 + llo, r, v0);
                float v1 = acc1a[i][1][rg] + bb1;
                v1 = 0.5f * v1 * (1.0f + erff(v1 * 0.7071067811865475f));
                sput(AH, wave * 32 + 16 + llo, r, v1);
            }
    }
    __syncthreads();
    // P8: F2.k0 (Wb0, AH slab0)
    mma_phase(AH, Wb0, acc2, llo, lhi, wave);
    __syncthreads();
    // P9: F2.k1 (Wb1, AH slab1); issue w1.n1.k0
    stageW(Wb0, w1 + 16384, 128, 0);
    mma_phase(AH + 4096, Wb1, acc2, llo, lhi, wave);
    __syncthreads();
    // P10: F1 n1.k0 (Wb0); issue w1.n1.k1
    stageW(Wb1, w1 + 16384, 128, 64);
    mma_phase(Xbuf, Wb0, acc1b, llo, lhi, wave);
    __syncthreads();
    // P11: F1 n1.k1 (Wb1); issue w2.k2
    stageW(Wb0, w2, 256, 128);
    mma_phase(Xbuf + 4096, Wb1, acc1b, llo, lhi, wave);
    __syncthreads();
    // P12: GELU n1 -> AH (overwrite); issue w2.k3
    stageW(Wb1, w2, 256, 192);
    {
        float bb0 = b1p[128 + wave * 32 + llo];
        float bb1 = b1p[128 + wave * 32 + 16 + llo];
        #pragma unroll
        for (int i = 0; i < 4; ++i)
            #pragma unroll
            for (int rg = 0; rg < 4; ++rg) {
                int r = i * 16 + lhi * 4 + rg;
                float v0 = acc1b[i][0][rg] + bb0;
                v0 = 0.5f * v0 * (1.0f + erff(v0 * 0.7071067811865475f));
                sput(AH, wave * 32 + llo, r, v0);
                float v1 = acc1b[i][1][rg] + bb1;
                v1 = 0.5f * v1 * (1.0f + erff(v1 * 0.7071067811865475f));
                sput(AH, wave * 32 + 16 + llo, r, v1);
            }
    }
    __syncthreads();
    // P13: F2.k2 (Wb0, AH slab0)
    mma_phase(AH, Wb0, acc2, llo, lhi, wave);
    __syncthreads();
    // P14: F2.k3 (Wb1, AH slab1)
    mma_phase(AH + 4096, Wb1, acc2, llo, lhi, wave);

    // LN2 (residual = post-LN1 x in acc0)
    {
        float b20 = b2p[wave * 32 + llo];
        float b21 = b2p[wave * 32 + 16 + llo];
        #pragma unroll
        for (int i = 0; i < 4; ++i)
            #pragma unroll
            for (int rg = 0; rg < 4; ++rg) {
                float x0 = acc0[i][0][rg] + acc2[i][0][rg] + b20;
                float x1 = acc0[i][1][rg] + acc2[i][1][rg] + b21;
                acc2[i][0][rg] = x0; acc2[i][1][rg] = x1;
                float s1 = x0 + x1, s2 = x0 * x0 + x1 * x1;
                #pragma unroll
                for (int off = 1; off < 16; off <<= 1) {
                    s1 += __shfl_xor(s1, off);
                    s2 += __shfl_xor(s2, off);
                }
                if (llo == 0) lnsum[i * 16 + lhi * 4 + rg][wave] = make_float2(s1, s2);
            }
    }
    __syncthreads();
    {
        float gg0 = lng2[wave * 32 + llo],      bb0 = lnb2[wave * 32 + llo];
        float gg1 = lng2[wave * 32 + 16 + llo], bb1 = lnb2[wave * 32 + 16 + llo];
        #pragma unroll
        for (int i = 0; i < 4; ++i)
            #pragma unroll
            for (int rg = 0; rg < 4; ++rg) {
                int r = i * 16 + lhi * 4 + rg;
                int m = m0 + r;
                if (m >= M) continue;
                float2 t0 = lnsum[r][0], t1 = lnsum[r][1], t2 = lnsum[r][2], t3 = lnsum[r][3];
                float mu = (t0.x + t1.x + t2.x + t3.x) * 0.0078125f;
                float var = fmaxf((t0.y + t1.y + t2.y + t3.y) * 0.0078125f - mu * mu, 0.f);
                float inv = rsqrtf(var + 1e-5f);
                float v0 = (acc2[i][0][rg] - mu) * inv * gg0 + bb0;
                float v1 = (acc2[i][1][rg] - mu) * inv * gg1 + bb1;
                size_t base = (size_t)m * 128 + wave * 32 + llo;
                feat[base] = v0;       feat[base + 16] = v1;
                featb[base] = f2bf(v0); featb[base + 16] = f2bf(v1);
            }
    }
}

// ------------------- BEV scatter into padded canvas (bf16, stride 420)
__global__ __launch_bounds__(256) void scatter_kernel(const float* __restrict__ feat,
    const int* __restrict__ coors, unsigned short* __restrict__ canvas)
{
    int idx = blockIdx.x * 256 + threadIdx.x;
    if (idx >= NVOX * 16) return;
    int n = idx >> 4, c8 = (idx & 15) << 3;
    int b = coors[n * 4], y = coors[n * 4 + 2], x = coors[n * 4 + 3];
    const float* src = feat + (size_t)n * 128 + c8;
    float4 u0 = *reinterpret_cast<const float4*>(src);
    float4 u1 = *reinterpret_cast<const float4*>(src + 4);
    ushort8v v;
    v[0]=f2bf(u0.x); v[1]=f2bf(u0.y); v[2]=f2bf(u0.z); v[3]=f2bf(u0.w);
    v[4]=f2bf(u1.x); v[5]=f2bf(u1.y); v[6]=f2bf(u1.z); v[7]=f2bf(u1.w);
    size_t p = (((size_t)b * 404 + y + 2) * 420 + x + 2) * 128 + c8;
    *reinterpret_cast<ushort8v*>(canvas + p) = v;
}

// --------- zero the halo of a stride-420 padded canvas
__global__ __launch_bounds__(256) void halo_zero(unsigned short* __restrict__ c) {
    int idx = blockIdx.x * 256 + threadIdx.x;
    if (idx >= 2 * 9680 * 16) return;
    int b = idx / (9680 * 16);
    int rem = idx % (9680 * 16);
    int p = rem >> 4, ch = (rem & 15) * 8;
    int y, x;
    if (p < 1680) { int ry = p / 420; y = (ry < 2) ? ry : ry + 400; x = p % 420; }
    else { int q = p - 1680; y = 2 + q / 20; int cx = q % 20; x = (cx < 2) ? cx : cx + 400; }
    ushort8v z = {};
    *reinterpret_cast<ushort8v*>(c + (((size_t)b * 404 + y) * 420 + x) * 128 + ch) = z;
}

// ------------------- conv weight re-layout -> bf16 [i][ky*3+kx][cout][cin]
__global__ __launch_bounds__(256) void wtrans_kernel(const float* __restrict__ cw,
                                                     unsigned short* __restrict__ wbuf)
{
    int idx = blockIdx.x * 256 + threadIdx.x;
    if (idx >= 2 * 9 * 128 * 128) return;
    int ci = idx & 127;
    int co = (idx >> 7) & 127;
    int kk = (idx >> 14) % 9;
    int i  = idx / (9 * 16384);
    wbuf[idx] = f2bf(cw[(((size_t)i * 128 + co) * 128 + ci) * 9 + kk]);
}

// ---------------- 3x3 dilated(2) conv + BN + ReLU, LDS-A once + LDS-W double-buffered
template<bool NCHW_OUT>
__global__ __launch_bounds__(512, 1) void conv_mfma(
    const unsigned short* __restrict__ in, const unsigned short* __restrict__ wbuf,
    const float* __restrict__ g, const float* __restrict__ bsh,
    const float* __restrict__ bm, const float* __restrict__ bv,
    void* __restrict__ out)
{
    __shared__ unsigned short Ab[8 * 36 * 128];
    __shared__ unsigned short Wb[2 * 128 * 128];
    const int tid = threadIdx.x;
    const int lane = tid & 63, wave = tid >> 6;
    const int cog = wave & 1, yg = wave >> 1;
    const int llo = lane & 15, lhi = lane >> 4;
    const int x0 = blockIdx.x * 32, y0 = blockIdx.y * 4, b = blockIdx.z;
    const int c16s = lane & 15;

    #pragma unroll
    for (int it = 0; it < 9; ++it) {
        int gidx = it * 32 + wave * 4 + lhi;
        int row = gidx / 36, xi = gidx % 36;
        gll16(in + (((size_t)b * 404 + y0 + row) * 420 + x0 + xi) * 128 + ((c16s ^ (xi & 15)) * 8),
              Ab + (size_t)(it * 512 + wave * 64) * 8);
    }
    {
        const unsigned short* wt = wbuf;
        #pragma unroll
        for (int it = 0; it < 4; ++it) {
            int co = it * 32 + wave * 4 + lhi;
            gll16(wt + co * 128 + ((c16s ^ (co & 15)) * 8),
                  Wb + (size_t)(it * 512 + wave * 64) * 8);
        }
    }
    __syncthreads();

    f32x4 acc[2][4] = {};
    #pragma unroll
    for (int t = 0; t < 9; ++t) {
        if (t < 8) {
            const unsigned short* wt = wbuf + (size_t)(t + 1) * 16384;
            unsigned short* dst = Wb + ((t + 1) & 1) * 16384;
            #pragma unroll
            for (int it = 0; it < 4; ++it) {
                int co = it * 32 + wave * 4 + lhi;
                gll16(wt + co * 128 + ((c16s ^ (co & 15)) * 8),
                      dst + (size_t)(it * 512 + wave * 64) * 8);
            }
        }
        const unsigned short* Wp = Wb + (t & 1) * 16384;
        const int ky = t / 3, kx = t % 3;
        const int r = yg + 2 * ky;
        #pragma unroll
        for (int kk = 0; kk < 4; ++kk) {
            short8v a[2], w[4];
            #pragma unroll
            for (int i = 0; i < 2; ++i) {
                int xi = i * 16 + llo + 2 * kx;
                a[i] = *reinterpret_cast<const short8v*>(
                    (const char*)Ab + (r * 36 + xi) * 256 + ((kk * 64 + lhi * 16) ^ ((xi & 15) << 4)));
            }
            #pragma unroll
            for (int j = 0; j < 4; ++j) {
                int co = cog * 64 + j * 16 + llo;
                w[j] = *reinterpret_cast<const short8v*>(
                    (const char*)Wp + co * 256 + ((kk * 64 + lhi * 16) ^ ((co & 15) << 4)));
            }
            #pragma unroll
            for (int i = 0; i < 2; ++i)
                #pragma unroll
                for (int j = 0; j < 4; ++j)
                    acc[i][j] = __builtin_amdgcn_mfma_f32_16x16x32_bf16(a[i], w[j], acc[i][j], 0, 0, 0);
        }
        __syncthreads();
    }

    const int y = y0 + yg;
    if (NCHW_OUT) {
        #pragma unroll
        for (int j = 0; j < 4; ++j) {
            int co = cog * 64 + j * 16 + llo;
            float scale = rsqrtf(bv[co] + 1e-3f) * g[co];
            float shift = bsh[co] - bm[co] * scale;
            #pragma unroll
            for (int i = 0; i < 2; ++i) {
                int px = x0 + i * 16 + lhi * 4;
                if (px < 400) {
                    float4 v;
                    v.x = fmaxf(acc[i][j][0] * scale + shift, 0.f);
                    v.y = fmaxf(acc[i][j][1] * scale + shift, 0.f);
                    v.z = fmaxf(acc[i][j][2] * scale + shift, 0.f);
                    v.w = fmaxf(acc[i][j][3] * scale + shift, 0.f);
                    *reinterpret_cast<float4*>(
                        (float*)out + (((size_t)b * 128 + co) * 400 + y) * 400 + px) = v;
                }
            }
        }
    } else {
        unsigned short* Cw = Wb + wave * 2048;
        #pragma unroll
        for (int j = 0; j < 4; ++j) {
            int co = cog * 64 + j * 16 + llo;
            float scale = rsqrtf(bv[co] + 1e-3f) * g[co];
            float shift = bsh[co] - bm[co] * scale;
            #pragma unroll
            for (int i = 0; i < 2; ++i)
                #pragma unroll
                for (int rg = 0; rg < 4; ++rg)
                    Cw[(i * 16 + lhi * 4 + rg) * 64 + j * 16 + llo] =
                        f2bf(fmaxf(acc[i][j][rg] * scale + shift, 0.f));
        }
        #pragma unroll
        for (int s = 0; s < 4; ++s) {
            int pxl = s * 8 + (lane >> 3);
            int oct = lane & 7;
            int px = x0 + pxl;
            if (px < 400)
                *reinterpret_cast<ushort8v*>(
                    (unsigned short*)out + (((size_t)b * 404 + y + 2) * 420 + px + 2) * 128
                                         + cog * 64 + oct * 8) =
                    *reinterpret_cast<const ushort8v*>(&Cw[pxl * 64 + oct * 8]);
        }
    }
}

// ---------------------------------------------------------------- launcher
extern "C" void kernel_launch(void* const* d_in, const int* in_sizes, int n_in,
                              void* d_out, int out_size, void* d_ws, size_t ws_size,
                              hipStream_t stream) {
    const float* voxel_feat = (const float*)d_in[0];
    const int*   coors      = (const int*)d_in[1];
    const float* ciw0       = (const float*)d_in[2];
    const float* ciw1       = (const float*)d_in[3];
    const int* vx[2][2] = {{(const int*)d_in[4], (const int*)d_in[6]},
                           {(const int*)d_in[8], (const int*)d_in[10]}};
    const float* ipw = (const float*)d_in[12];
    const float* ipb = (const float*)d_in[13];
    const float* ow  = (const float*)d_in[14];
    const float* obp = (const float*)d_in[15];
    const float* l1w = (const float*)d_in[16];
    const float* l1b = (const float*)d_in[17];
    const float* l2w = (const float*)d_in[18];
    const float* l2b = (const float*)d_in[19];
    const float* g1  = (const float*)d_in[20];
    const float* b1  = (const float*)d_in[21];
    const float* g2  = (const float*)d_in[22];
    const float* b2  = (const float*)d_in[23];
    const float* cw  = (const float*)d_in[24];
    const float* bng = (const float*)d_in[25];
    const float* bnb = (const float*)d_in[26];
    const float* bnm = (const float*)d_in[27];
    const float* bnv = (const float*)d_in[28];

    float* F = (float*)d_ws;
    unsigned short* W0   = (unsigned short*)F;
    unsigned short* ipwb = W0;                           // 589824
    unsigned short* owb  = W0 + 589824;                  // 196608
    unsigned short* l1wb = W0 + 786432;                  // 393216
    unsigned short* l2wb = W0 + 1179648;                 // 393216
    unsigned short* cwb  = W0 + 1572864;                 // 294912
    float* feat = F + 940000;                            // 7.68M f32
    unsigned short* featb = (unsigned short*)(F + 8620000);
    unsigned short* pos0  = (unsigned short*)(F + 12460000);
    unsigned short* pos1  = (unsigned short*)(F + 16300000);
    unsigned short* obufb = (unsigned short*)(F + 20140000);
    unsigned short* canvas1 = (unsigned short*)(F + 8620000);
    unsigned short* canvas2 = (unsigned short*)(F + 30339040);
    unsigned short* qkvb = (unsigned short*)d_out;

    feat_init<<<30000, 256, 0, stream>>>(voxel_feat, feat, featb);
    pos_kernel<<<30000, 256, 0, stream>>>(ciw0, pos0);
    pos_kernel<<<30000, 256, 0, stream>>>(ciw1, pos1);
    cvt_bf16<<<(589824 + 255) / 256, 256, 0, stream>>>(ipw, ipwb, 589824);
    cvt_bf16<<<(196608 + 255) / 256, 256, 0, stream>>>(ow,  owb,  196608);
    cvt_bf16<<<(393216 + 255) / 256, 256, 0, stream>>>(l1w, l1wb, 393216);
    cvt_bf16<<<(393216 + 255) / 256, 256, 0, stream>>>(l2w, l2wb, 393216);
    wtrans_kernel<<<(2 * 9 * 16384 + 255) / 256, 256, 0, stream>>>(cw, cwb);

    for (int li = 0; li < 12; ++li) {
        int s = li & 1;
        const unsigned short* pos = s ? pos1 : pos0;
        gemm_mfma<128, true, false, true, false><<<dim3(469, 3), 256, 0, stream>>>(
            featb, pos, 2, ipwb + (size_t)li * 49152, ipb + li * 384, qkvb, NVOX, 384);
        attn_kernel<25, 8><<<dim3(960, 1), 256, 0, stream>>>(qkvb, vx[s][0], 24000, obufb);
        attn_kernel<100, 2><<<dim3(360, 4), 256, 0, stream>>>(qkvb, vx[s][1], 36000, obufb);
        fused_tail<<<938, 256, 0, stream>>>(
            obufb, owb + (size_t)li * 16384, obp + li * 128,
            l1wb + (size_t)li * 32768, l1b + li * 256,
            l2wb + (size_t)li * 32768, l2b + li * 128,
            g1 + li * 128, b1 + li * 128, g2 + li * 128, b2 + li * 128,
            feat, featb, NVOX);
    }

    hipMemsetAsync(canvas1, 0, (size_t)43438080 * 2, stream);
    halo_zero<<<(2 * 9680 * 16 + 255) / 256, 256, 0, stream>>>(canvas2);
    scatter_kernel<<<(NVOX * 16 + 255) / 256, 256, 0, stream>>>(feat, coors, canvas1);
    conv_mfma<false><<<dim3(13, 100, 2), 512, 0, stream>>>(
        canvas1, cwb, bng, bnb, bnm, bnv, canvas2);
    conv_mfma<true><<<dim3(13, 100, 2), 512, 0, stream>>>(
        canvas2, cwb + 9 * 16384, bng + 128, bnb + 128, bnm + 128, bnv + 128, (float*)d_out);
}